// Round 1
// baseline (113.183 us; speedup 1.0000x reference)
//
#include <hip/hip_runtime.h>

#define HW     16384      // H*W = 128*128
#define NP     17         // n_parts
#define CCH    34         // channels = (1+TAG_DIM)*n_parts
#define BB     8
#define SS     4
#define NPERS  30
#define NBS    (BB*SS)                 // 32
#define NDET4  (NBS*NP*(HW/4))         // 2,228,224 float4 elements
#define DETBLOCKS 1088
#define LOSS_EPS 1e-6f

// --- block tree reduction (blockDim.x threads, up to 512) ---
__device__ __forceinline__ float block_reduce_sum(float v, float* sred) {
    // wave-level reduce (wave = 64 on gfx950)
    for (int off = 32; off > 0; off >>= 1)
        v += __shfl_down(v, off, 64);
    const int lane = threadIdx.x & 63;
    const int wave = threadIdx.x >> 6;
    if (lane == 0) sred[wave] = v;
    __syncthreads();
    if (threadIdx.x == 0) {
        float s = 0.f;
        const int nw = blockDim.x >> 6;
        for (int i = 0; i < nw; i++) s += sred[i];
        sred[0] = s;
    }
    __syncthreads();
    return sred[0];
}

// ---------------- kernel 1: det partial sums ----------------
// sum over (b,s,p,h,w) of (preds_det - heatmap)^2 * mask
__global__ __launch_bounds__(256) void k_det(const float* __restrict__ preds,
                                             const float* __restrict__ masks,
                                             const float* __restrict__ heat,
                                             float* __restrict__ partial) {
    __shared__ float sred[4];
    float acc = 0.f;
    const int stride = gridDim.x * blockDim.x;
    for (int e4 = blockIdx.x * blockDim.x + threadIdx.x; e4 < NDET4; e4 += stride) {
        const int hw4   = e4 & ((HW / 4) - 1);   // HW/4 = 4096 = 2^12
        const int plane = e4 >> 12;              // bs*NP + p
        const int bs    = plane / NP;
        const int p     = plane - bs * NP;
        const int b     = bs >> 2;               // SS = 4
        const float4 d = *(const float4*)(preds + ((size_t)bs * CCH + p) * HW + (size_t)hw4 * 4);
        const float4 h = *(const float4*)(heat  + ((size_t)b * NP + p) * HW + (size_t)hw4 * 4);
        const float4 m = *(const float4*)(masks + (size_t)b * HW + (size_t)hw4 * 4);
        float dx = d.x - h.x, dy = d.y - h.y, dz = d.z - h.z, dw = d.w - h.w;
        acc += dx * dx * m.x + dy * dy * m.y + dz * dz * m.z + dw * dw * m.w;
    }
    float tot = block_reduce_sum(acc, sred);
    if (threadIdx.x == 0) partial[blockIdx.x] = tot;
}

// ---------------- kernel 2: push/pull per (b,s) ----------------
__global__ __launch_bounds__(256) void k_group(const float* __restrict__ preds,
                                               const int* __restrict__ kp,
                                               float* __restrict__ pull_out,
                                               float* __restrict__ push_out) {
    __shared__ float sg[NPERS * NP];    // gathered tag values
    __shared__ float svis[NPERS * NP];  // visibility 0/1
    __shared__ float smean[NPERS];
    __shared__ float scnt[NPERS];
    __shared__ float spull[NPERS];
    __shared__ float sred[4];
    __shared__ float snum;

    const int bs = blockIdx.x;      // b*SS + s
    const int b  = bs >> 2;
    const int tid = threadIdx.x;
    // tag base for this (b,s): channel offset NP within CCH channels
    const size_t tag_base = ((size_t)bs * CCH + NP) * HW;

    // load keypoints (idx, vis) and gather tag values
    for (int t = tid; t < NPERS * NP; t += 256) {
        const int kbase = (b * NPERS * NP + t) * 2;  // ((b*30+person)*17+part)*2
        int ii = kp[kbase];
        const int vv = kp[kbase + 1];
        if (ii < 0) ii = 0;
        if (ii >= NP * HW) ii = NP * HW - 1;         // jnp.take clip semantics
        svis[t] = (vv > 0) ? 1.f : 0.f;
        sg[t]   = preds[tag_base + (size_t)ii];
    }
    __syncthreads();

    // per-person count / mean / pull_pp
    if (tid < NPERS) {
        float c = 0.f, msum = 0.f;
        for (int k = 0; k < NP; k++) {
            c    += svis[tid * NP + k];
            msum += sg[tid * NP + k] * svis[tid * NP + k];
        }
        const float sc = fmaxf(c, 1.f);
        const float m = msum / sc;
        float pp = 0.f;
        for (int k = 0; k < NP; k++) {
            const float dd = sg[tid * NP + k] - m;
            pp += dd * dd * svis[tid * NP + k];
        }
        scnt[tid]  = c;
        smean[tid] = m;
        spull[tid] = pp / sc;   // TAG_DIM = 1
    }
    __syncthreads();

    if (tid == 0) {
        float num = 0.f, psum = 0.f;
        for (int i = 0; i < NPERS; i++) {
            if (scnt[i] > 0.f) { num += 1.f; psum += spull[i]; }
        }
        snum = num;
        pull_out[bs] = psum / (num + LOSS_EPS);
    }
    __syncthreads();

    // push: 30x30 pair matrix
    float pacc = 0.f;
    for (int t = tid; t < NPERS * NPERS; t += 256) {
        const int i = t / NPERS;
        const int j = t - i * NPERS;
        const float vi = (scnt[i] > 0.f) ? 1.f : 0.f;
        const float vj = (scnt[j] > 0.f) ? 1.f : 0.f;
        const float d = smean[i] - smean[j];
        pacc += expf(-d * d) * vi * vj;
    }
    const float ptot = block_reduce_sum(pacc, sred);
    if (tid == 0) {
        const float num = snum;
        push_out[bs] = (ptot - num) / ((num - 1.f) * num + LOSS_EPS) * 0.5f;
    }
}

// ---------------- kernel 3: final combine ----------------
__global__ __launch_bounds__(256) void k_final(const float* __restrict__ partial,
                                               const float* __restrict__ pull_v,
                                               const float* __restrict__ push_v,
                                               float* __restrict__ out) {
    __shared__ float sred[4];
    float a = 0.f;
    for (int i = threadIdx.x; i < DETBLOCKS; i += 256) a += partial[i];
    const float det_sum = block_reduce_sum(a, sred);
    if (threadIdx.x == 0) {
        float pl = 0.f, ph = 0.f;
        for (int i = 0; i < NBS; i++) { pl += pull_v[i]; ph += push_v[i]; }
        const float det_mean = det_sum / (float)((size_t)NBS * NP * HW);  // /8,912,896
        const float loss = 0.001f * (ph / (float)NBS)
                         + 0.001f * (pl / (float)NBS)
                         + det_mean;
        out[0] = loss;
    }
}

extern "C" void kernel_launch(void* const* d_in, const int* in_sizes, int n_in,
                              void* d_out, int out_size, void* d_ws, size_t ws_size,
                              hipStream_t stream) {
    const float* preds = (const float*)d_in[0];
    const float* masks = (const float*)d_in[1];
    const float* heat  = (const float*)d_in[2];
    const int*   kp    = (const int*)d_in[3];
    float* out = (float*)d_out;
    float* ws  = (float*)d_ws;
    // ws layout: [0..1087] det partials | [1088..1119] pull | [1120..1151] push
    k_det<<<DETBLOCKS, 256, 0, stream>>>(preds, masks, heat, ws);
    k_group<<<NBS, 256, 0, stream>>>(preds, kp, ws + DETBLOCKS, ws + DETBLOCKS + NBS);
    k_final<<<1, 256, 0, stream>>>(ws, ws + DETBLOCKS, ws + DETBLOCKS + NBS, out);
}